// Round 1
// baseline (8251.909 us; speedup 1.0000x reference)
//
#include <hip/hip_runtime.h>
#include <math.h>

#define BB 32
#define SS 2048
#define HH 1024
#define MT (BB*SS)      // 65536 rows

#define BM 128
#define BN 128
#define KC 16
#define NCH (HH/BN)     // 8 n-chunks

// ---------------- Kernel 1: dec_proj[b][n] = dh[b]·Wa_w[:,n] + Wa_b[n] + Ua_b[n]
__global__ void dec_proj_kernel(const float* __restrict__ dh,
                                const float* __restrict__ Wa_w,
                                const float* __restrict__ Wa_b,
                                const float* __restrict__ Ua_b,
                                float* __restrict__ dec_proj) {
    __shared__ float sdh[HH];
    const int b   = blockIdx.x;
    const int nq  = blockIdx.y;           // 0..3
    const int tid = threadIdx.x;          // 256
    for (int i = tid; i < HH; i += 256) sdh[i] = dh[b*HH + i];
    __syncthreads();
    const int n = nq*256 + tid;
    float acc = Wa_b[n] + Ua_b[n];
    for (int k = 0; k < HH; ++k)
        acc = fmaf(sdh[k], Wa_w[(size_t)k*HH + n], acc);
    dec_proj[b*HH + n] = acc;
}

// ---------------- Kernel 2: fused enc@Ua GEMM + tanh + Va-dot -> partials[M][NCH]
__global__ __launch_bounds__(256, 2)
void fused_gemm_kernel(const float* __restrict__ A,      // enc [M, H]
                       const float* __restrict__ W,      // Ua  [H(k), H(n)]
                       const float* __restrict__ dec_proj,// [B, H] (biases folded)
                       const float* __restrict__ Va_w,   // [H]
                       float* __restrict__ partials)     // [M, NCH]
{
    __shared__ float As[2][KC][BM];   // transposed: As[k][m]
    __shared__ float Ws[2][KC][BN];   // Ws[k][n]
    const int nch = blockIdx.x;           // 0..7
    const int m0  = blockIdx.y * BM;
    const int n0  = nch * BN;
    const int tid = threadIdx.x;
    const int tx  = tid & 15;             // n-direction (8 cols each)
    const int ty  = tid >> 4;             // m-direction (8 rows each)

    // staging decomposition
    const int arow = tid >> 2;            // 0..63
    const int aq   = (tid & 3) * 4;       // k offset within chunk
    const int wrow = tid >> 5;            // 0..7
    const int wq   = (tid & 31) * 4;      // n offset

    float acc[8][8];
    #pragma unroll
    for (int i = 0; i < 8; ++i)
        #pragma unroll
        for (int j = 0; j < 8; ++j) acc[i][j] = 0.f;

    float4 av0, av1, wv0, wv1;
    // prologue: chunk 0 -> buf 0
    av0 = *(const float4*)&A[(size_t)(m0+arow   )*HH + 0 + aq];
    av1 = *(const float4*)&A[(size_t)(m0+arow+64)*HH + 0 + aq];
    wv0 = *(const float4*)&W[(size_t)(0+wrow  )*HH + n0 + wq];
    wv1 = *(const float4*)&W[(size_t)(0+wrow+8)*HH + n0 + wq];
    As[0][aq+0][arow]    = av0.x; As[0][aq+1][arow]    = av0.y;
    As[0][aq+2][arow]    = av0.z; As[0][aq+3][arow]    = av0.w;
    As[0][aq+0][arow+64] = av1.x; As[0][aq+1][arow+64] = av1.y;
    As[0][aq+2][arow+64] = av1.z; As[0][aq+3][arow+64] = av1.w;
    *(float4*)&Ws[0][wrow  ][wq] = wv0;
    *(float4*)&Ws[0][wrow+8][wq] = wv1;
    __syncthreads();

    int buf = 0;
    for (int kc = KC; kc <= HH; kc += KC) {   // kc = NEXT chunk base
        const bool has_next = (kc < HH);
        if (has_next) {
            av0 = *(const float4*)&A[(size_t)(m0+arow   )*HH + kc + aq];
            av1 = *(const float4*)&A[(size_t)(m0+arow+64)*HH + kc + aq];
            wv0 = *(const float4*)&W[(size_t)(kc+wrow  )*HH + n0 + wq];
            wv1 = *(const float4*)&W[(size_t)(kc+wrow+8)*HH + n0 + wq];
        }
        #pragma unroll
        for (int kk = 0; kk < KC; ++kk) {
            const float4 a0 = *(const float4*)&As[buf][kk][ty*8];
            const float4 a1 = *(const float4*)&As[buf][kk][ty*8+4];
            const float4 w0 = *(const float4*)&Ws[buf][kk][tx*8];
            const float4 w1 = *(const float4*)&Ws[buf][kk][tx*8+4];
            const float a[8] = {a0.x,a0.y,a0.z,a0.w,a1.x,a1.y,a1.z,a1.w};
            const float w[8] = {w0.x,w0.y,w0.z,w0.w,w1.x,w1.y,w1.z,w1.w};
            #pragma unroll
            for (int i = 0; i < 8; ++i)
                #pragma unroll
                for (int j = 0; j < 8; ++j)
                    acc[i][j] = fmaf(a[i], w[j], acc[i][j]);
        }
        if (has_next) {
            const int nb = buf ^ 1;
            As[nb][aq+0][arow]    = av0.x; As[nb][aq+1][arow]    = av0.y;
            As[nb][aq+2][arow]    = av0.z; As[nb][aq+3][arow]    = av0.w;
            As[nb][aq+0][arow+64] = av1.x; As[nb][aq+1][arow+64] = av1.y;
            As[nb][aq+2][arow+64] = av1.z; As[nb][aq+3][arow+64] = av1.w;
            *(float4*)&Ws[nb][wrow  ][wq] = wv0;
            *(float4*)&Ws[nb][wrow+8][wq] = wv1;
        }
        __syncthreads();
        buf ^= 1;
    }

    // epilogue: tanh(acc + dp[n]) · Va[n], reduce over this block's 128 n-cols
    const int bidx = m0 >> 11;            // 2048 rows per batch; 128 | 2048
    float dpv[8], vav[8], rowsum[8];
    #pragma unroll
    for (int j = 0; j < 8; ++j) {
        const int n = n0 + tx*8 + j;
        dpv[j] = dec_proj[bidx*HH + n];
        vav[j] = Va_w[n];
    }
    #pragma unroll
    for (int i = 0; i < 8; ++i) rowsum[i] = 0.f;
    #pragma unroll
    for (int i = 0; i < 8; ++i)
        #pragma unroll
        for (int j = 0; j < 8; ++j)
            rowsum[i] += vav[j] * tanhf(acc[i][j] + dpv[j]);
    #pragma unroll
    for (int off = 1; off < 16; off <<= 1)
        #pragma unroll
        for (int i = 0; i < 8; ++i)
            rowsum[i] += __shfl_xor(rowsum[i], off, 64);
    if (tx == 0) {
        #pragma unroll
        for (int i = 0; i < 8; ++i)
            partials[(size_t)(m0 + ty*8 + i)*NCH + nch] = rowsum[i];
    }
}

// ---------------- Kernel 3: sum partials + Va_b, mask, softmax over S
__global__ void softmax_kernel(const float* __restrict__ partials,
                               const int* __restrict__ mask,
                               const float* __restrict__ vb_ptr,
                               float* __restrict__ out)
{
    const int b   = blockIdx.x;
    const int tid = threadIdx.x;   // 256, each handles 8 s-positions
    __shared__ float sred[8];
    const float vb = vb_ptr[0];
    float sc[8];
    float mymax = -INFINITY;
    #pragma unroll
    for (int i = 0; i < 8; ++i) {
        const int s = i*256 + tid;
        const float4* p = (const float4*)&partials[((size_t)b*SS + s)*NCH];
        const float4 x = p[0], y = p[1];
        float v = ((x.x+x.y)+(x.z+x.w)) + ((y.x+y.y)+(y.z+y.w)) + vb;
        if (mask[b*SS + s] == 0) v = -1e9f;
        sc[i] = v;
        mymax = fmaxf(mymax, v);
    }
    #pragma unroll
    for (int off = 1; off < 64; off <<= 1)
        mymax = fmaxf(mymax, __shfl_xor(mymax, off, 64));
    const int wave = tid >> 6, lane = tid & 63;
    if (lane == 0) sred[wave] = mymax;
    __syncthreads();
    const float bmax = fmaxf(fmaxf(sred[0], sred[1]), fmaxf(sred[2], sred[3]));
    float ex[8], mysum = 0.f;
    #pragma unroll
    for (int i = 0; i < 8; ++i) {
        ex[i] = __expf(sc[i] - bmax);
        mysum += ex[i];
    }
    #pragma unroll
    for (int off = 1; off < 64; off <<= 1)
        mysum += __shfl_xor(mysum, off, 64);
    if (lane == 0) sred[4 + wave] = mysum;
    __syncthreads();
    const float inv = 1.f / (sred[4] + sred[5] + sred[6] + sred[7]);
    #pragma unroll
    for (int i = 0; i < 8; ++i)
        out[(size_t)b*SS + i*256 + tid] = ex[i] * inv;
}

extern "C" void kernel_launch(void* const* d_in, const int* in_sizes, int n_in,
                              void* d_out, int out_size, void* d_ws, size_t ws_size,
                              hipStream_t stream) {
    const float* dh   = (const float*)d_in[0];
    const float* enc  = (const float*)d_in[1];
    const int*   mask = (const int*)d_in[2];
    const float* Wa_w = (const float*)d_in[3];
    const float* Wa_b = (const float*)d_in[4];
    const float* Ua_w = (const float*)d_in[5];
    const float* Ua_b = (const float*)d_in[6];
    const float* Va_w = (const float*)d_in[7];
    const float* Va_b = (const float*)d_in[8];
    float* out = (float*)d_out;

    float* dec_proj = (float*)d_ws;                 // [B,H]   = 128 KB
    float* partials = dec_proj + BB*HH;             // [M,NCH] = 2 MB

    dec_proj_kernel<<<dim3(BB, 4), 256, 0, stream>>>(dh, Wa_w, Wa_b, Ua_b, dec_proj);
    fused_gemm_kernel<<<dim3(NCH, MT/BM), 256, 0, stream>>>(enc, Ua_w, dec_proj, Va_w, partials);
    softmax_kernel<<<BB, 256, 0, stream>>>(partials, mask, Va_b, out);
}

// Round 2
// 2467.045 us; speedup vs baseline: 3.3449x; 3.3449x over previous
//
#include <hip/hip_runtime.h>
#include <math.h>

#define BB 32
#define SS 2048
#define HH 1024
#define MT (BB*SS)      // 65536 rows

#define BM 128
#define BN 128
#define KC 16
#define NCH (HH/BN)     // 8 n-chunks

// ---------------- Kernel 1: dec_proj[b][n] = dh[b]·Wa_w[:,n] + Wa_b[n] + Ua_b[n]
__global__ void dec_proj_kernel(const float* __restrict__ dh,
                                const float* __restrict__ Wa_w,
                                const float* __restrict__ Wa_b,
                                const float* __restrict__ Ua_b,
                                float* __restrict__ dec_proj) {
    __shared__ float sdh[HH];
    const int b   = blockIdx.x;
    const int nq  = blockIdx.y;           // 0..3
    const int tid = threadIdx.x;          // 256
    for (int i = tid; i < HH; i += 256) sdh[i] = dh[b*HH + i];
    __syncthreads();
    const int n = nq*256 + tid;
    float acc = Wa_b[n] + Ua_b[n];
    for (int k = 0; k < HH; ++k)
        acc = fmaf(sdh[k], Wa_w[(size_t)k*HH + n], acc);
    dec_proj[b*HH + n] = acc;
}

// ---------------- Kernel 2: fused enc@Ua GEMM + tanh + Va-dot -> partials[M][NCH]
__global__ __launch_bounds__(256, 1)   // was (256,2): capped VGPR at 128 -> scratch spill, 27 GB HBM writes
void fused_gemm_kernel(const float* __restrict__ A,      // enc [M, H]
                       const float* __restrict__ W,      // Ua  [H(k), H(n)]
                       const float* __restrict__ dec_proj,// [B, H] (biases folded)
                       const float* __restrict__ Va_w,   // [H]
                       float* __restrict__ partials)     // [M, NCH]
{
    __shared__ float As[2][KC][BM];   // transposed: As[k][m]
    __shared__ float Ws[2][KC][BN];   // Ws[k][n]
    const int nch = blockIdx.x;           // 0..7
    const int m0  = blockIdx.y * BM;
    const int n0  = nch * BN;
    const int tid = threadIdx.x;
    const int tx  = tid & 15;             // n-direction (8 cols each)
    const int ty  = tid >> 4;             // m-direction (8 rows each)

    // staging decomposition
    const int arow = tid >> 2;            // 0..63
    const int aq   = (tid & 3) * 4;       // k offset within chunk
    const int wrow = tid >> 5;            // 0..7
    const int wq   = (tid & 31) * 4;      // n offset

    float acc[8][8];
    #pragma unroll
    for (int i = 0; i < 8; ++i)
        #pragma unroll
        for (int j = 0; j < 8; ++j) acc[i][j] = 0.f;

    float4 av0, av1, wv0, wv1;
    // prologue: chunk 0 -> buf 0
    av0 = *(const float4*)&A[(size_t)(m0+arow   )*HH + 0 + aq];
    av1 = *(const float4*)&A[(size_t)(m0+arow+64)*HH + 0 + aq];
    wv0 = *(const float4*)&W[(size_t)(0+wrow  )*HH + n0 + wq];
    wv1 = *(const float4*)&W[(size_t)(0+wrow+8)*HH + n0 + wq];
    As[0][aq+0][arow]    = av0.x; As[0][aq+1][arow]    = av0.y;
    As[0][aq+2][arow]    = av0.z; As[0][aq+3][arow]    = av0.w;
    As[0][aq+0][arow+64] = av1.x; As[0][aq+1][arow+64] = av1.y;
    As[0][aq+2][arow+64] = av1.z; As[0][aq+3][arow+64] = av1.w;
    *(float4*)&Ws[0][wrow  ][wq] = wv0;
    *(float4*)&Ws[0][wrow+8][wq] = wv1;
    __syncthreads();

    int buf = 0;
    for (int kc = KC; kc <= HH; kc += KC) {   // kc = NEXT chunk base
        const bool has_next = (kc < HH);
        if (has_next) {
            av0 = *(const float4*)&A[(size_t)(m0+arow   )*HH + kc + aq];
            av1 = *(const float4*)&A[(size_t)(m0+arow+64)*HH + kc + aq];
            wv0 = *(const float4*)&W[(size_t)(kc+wrow  )*HH + n0 + wq];
            wv1 = *(const float4*)&W[(size_t)(kc+wrow+8)*HH + n0 + wq];
        }
        #pragma unroll
        for (int kk = 0; kk < KC; ++kk) {
            const float4 a0 = *(const float4*)&As[buf][kk][ty*8];
            const float4 a1 = *(const float4*)&As[buf][kk][ty*8+4];
            const float4 w0 = *(const float4*)&Ws[buf][kk][tx*8];
            const float4 w1 = *(const float4*)&Ws[buf][kk][tx*8+4];
            const float a[8] = {a0.x,a0.y,a0.z,a0.w,a1.x,a1.y,a1.z,a1.w};
            const float w[8] = {w0.x,w0.y,w0.z,w0.w,w1.x,w1.y,w1.z,w1.w};
            #pragma unroll
            for (int i = 0; i < 8; ++i)
                #pragma unroll
                for (int j = 0; j < 8; ++j)
                    acc[i][j] = fmaf(a[i], w[j], acc[i][j]);
        }
        if (has_next) {
            const int nb = buf ^ 1;
            As[nb][aq+0][arow]    = av0.x; As[nb][aq+1][arow]    = av0.y;
            As[nb][aq+2][arow]    = av0.z; As[nb][aq+3][arow]    = av0.w;
            As[nb][aq+0][arow+64] = av1.x; As[nb][aq+1][arow+64] = av1.y;
            As[nb][aq+2][arow+64] = av1.z; As[nb][aq+3][arow+64] = av1.w;
            *(float4*)&Ws[nb][wrow  ][wq] = wv0;
            *(float4*)&Ws[nb][wrow+8][wq] = wv1;
        }
        __syncthreads();
        buf ^= 1;
    }

    // epilogue: tanh(acc + dp[n]) · Va[n], reduce over this block's 128 n-cols
    const int bidx = m0 >> 11;            // 2048 rows per batch; 128 | 2048
    float dpv[8], vav[8], rowsum[8];
    #pragma unroll
    for (int j = 0; j < 8; ++j) {
        const int n = n0 + tx*8 + j;
        dpv[j] = dec_proj[bidx*HH + n];
        vav[j] = Va_w[n];
    }
    #pragma unroll
    for (int i = 0; i < 8; ++i) rowsum[i] = 0.f;
    #pragma unroll
    for (int i = 0; i < 8; ++i)
        #pragma unroll
        for (int j = 0; j < 8; ++j)
            rowsum[i] += vav[j] * tanhf(acc[i][j] + dpv[j]);
    #pragma unroll
    for (int off = 1; off < 16; off <<= 1)
        #pragma unroll
        for (int i = 0; i < 8; ++i)
            rowsum[i] += __shfl_xor(rowsum[i], off, 64);
    if (tx == 0) {
        #pragma unroll
        for (int i = 0; i < 8; ++i)
            partials[(size_t)(m0 + ty*8 + i)*NCH + nch] = rowsum[i];
    }
}

// ---------------- Kernel 3: sum partials + Va_b, mask, softmax over S
__global__ void softmax_kernel(const float* __restrict__ partials,
                               const int* __restrict__ mask,
                               const float* __restrict__ vb_ptr,
                               float* __restrict__ out)
{
    const int b   = blockIdx.x;
    const int tid = threadIdx.x;   // 256, each handles 8 s-positions
    __shared__ float sred[8];
    const float vb = vb_ptr[0];
    float sc[8];
    float mymax = -INFINITY;
    #pragma unroll
    for (int i = 0; i < 8; ++i) {
        const int s = i*256 + tid;
        const float4* p = (const float4*)&partials[((size_t)b*SS + s)*NCH];
        const float4 x = p[0], y = p[1];
        float v = ((x.x+x.y)+(x.z+x.w)) + ((y.x+y.y)+(y.z+y.w)) + vb;
        if (mask[b*SS + s] == 0) v = -1e9f;
        sc[i] = v;
        mymax = fmaxf(mymax, v);
    }
    #pragma unroll
    for (int off = 1; off < 64; off <<= 1)
        mymax = fmaxf(mymax, __shfl_xor(mymax, off, 64));
    const int wave = tid >> 6, lane = tid & 63;
    if (lane == 0) sred[wave] = mymax;
    __syncthreads();
    const float bmax = fmaxf(fmaxf(sred[0], sred[1]), fmaxf(sred[2], sred[3]));
    float ex[8], mysum = 0.f;
    #pragma unroll
    for (int i = 0; i < 8; ++i) {
        ex[i] = __expf(sc[i] - bmax);
        mysum += ex[i];
    }
    #pragma unroll
    for (int off = 1; off < 64; off <<= 1)
        mysum += __shfl_xor(mysum, off, 64);
    if (lane == 0) sred[4 + wave] = mysum;
    __syncthreads();
    const float inv = 1.f / (sred[4] + sred[5] + sred[6] + sred[7]);
    #pragma unroll
    for (int i = 0; i < 8; ++i)
        out[(size_t)b*SS + i*256 + tid] = ex[i] * inv;
}

extern "C" void kernel_launch(void* const* d_in, const int* in_sizes, int n_in,
                              void* d_out, int out_size, void* d_ws, size_t ws_size,
                              hipStream_t stream) {
    const float* dh   = (const float*)d_in[0];
    const float* enc  = (const float*)d_in[1];
    const int*   mask = (const int*)d_in[2];
    const float* Wa_w = (const float*)d_in[3];
    const float* Wa_b = (const float*)d_in[4];
    const float* Ua_w = (const float*)d_in[5];
    const float* Ua_b = (const float*)d_in[6];
    const float* Va_w = (const float*)d_in[7];
    const float* Va_b = (const float*)d_in[8];
    float* out = (float*)d_out;

    float* dec_proj = (float*)d_ws;                 // [B,H]   = 128 KB
    float* partials = dec_proj + BB*HH;             // [M,NCH] = 2 MB

    dec_proj_kernel<<<dim3(BB, 4), 256, 0, stream>>>(dh, Wa_w, Wa_b, Ua_b, dec_proj);
    fused_gemm_kernel<<<dim3(NCH, MT/BM), 256, 0, stream>>>(enc, Ua_w, dec_proj, Va_w, partials);
    softmax_kernel<<<BB, 256, 0, stream>>>(partials, mask, Va_b, out);
}

// Round 3
// 539.256 us; speedup vs baseline: 15.3024x; 4.5749x over previous
//
#include <hip/hip_runtime.h>
#include <math.h>

#define BB 32
#define SS 2048
#define HH 1024
#define MT (BB*SS)      // 65536 rows

#define BM 128
#define BN 128
#define BK 32
#define NT (HH/BK)      // 32 k-tiles
#define NCH (HH/BN)     // 8 n-chunks

typedef float  f32x4 __attribute__((ext_vector_type(4)));
typedef short  s16x8 __attribute__((ext_vector_type(8)));
typedef unsigned short u16;

// truncation split: x ~= hi + lo, |x - hi - lo| <= 2^-16 |x|
__device__ inline void split1(float x, u16& h, u16& l) {
    unsigned u = __float_as_uint(x);
    h = (u16)(u >> 16);
    float hf = __uint_as_float((u >> 16) << 16);
    l = (u16)(__float_as_uint(x - hf) >> 16);
}

// ---------------- Kernel 1: dec_proj[b][n] = dh[b]·Wa_w[:,n] + Wa_b[n] + Ua_b[n]
__global__ void dec_proj_kernel(const float* __restrict__ dh,
                                const float* __restrict__ Wa_w,
                                const float* __restrict__ Wa_b,
                                const float* __restrict__ Ua_b,
                                float* __restrict__ dec_proj) {
    __shared__ float sdh[HH];
    const int b   = blockIdx.x;
    const int nq  = blockIdx.y;           // 0..3
    const int tid = threadIdx.x;          // 256
    for (int i = tid; i < HH; i += 256) sdh[i] = dh[b*HH + i];
    __syncthreads();
    const int n = nq*256 + tid;
    float acc = Wa_b[n] + Ua_b[n];
    for (int k = 0; k < HH; ++k)
        acc = fmaf(sdh[k], Wa_w[(size_t)k*HH + n], acc);
    dec_proj[b*HH + n] = acc;
}

// ---------------- Kernel 2: Ua [K][N] -> Bh_t/Bl_t [N][K] split-bf16
__global__ void transpose_convert_kernel(const float* __restrict__ Ua,
                                         u16* __restrict__ Bh_t,
                                         u16* __restrict__ Bl_t) {
    __shared__ u16 shh[64][72], shl[64][72];
    const int nb = blockIdx.x * 64, kb = blockIdx.y * 64;
    const int tid = threadIdx.x;          // 256
    const int kl = tid >> 4, nl4 = (tid & 15) * 4;
    #pragma unroll
    for (int q = 0; q < 4; ++q) {
        const int k = kl + q*16;
        float4 v = *(const float4*)&Ua[(size_t)(kb + k)*HH + nb + nl4];
        float x[4] = {v.x, v.y, v.z, v.w};
        #pragma unroll
        for (int j = 0; j < 4; ++j) {
            u16 hh, ll; split1(x[j], hh, ll);
            shh[k][nl4 + j] = hh; shl[k][nl4 + j] = ll;
        }
    }
    __syncthreads();
    const int nl = tid >> 3, kc8 = (tid & 7) * 8;
    #pragma unroll
    for (int q = 0; q < 2; ++q) {
        const int n = nl + q*32;
        s16x8 hv, lv;
        #pragma unroll
        for (int j = 0; j < 8; ++j) { hv[j] = (short)shh[kc8 + j][n]; lv[j] = (short)shl[kc8 + j][n]; }
        *(s16x8*)&Bh_t[(size_t)(nb + n)*HH + kb + kc8] = hv;
        *(s16x8*)&Bl_t[(size_t)(nb + n)*HH + kb + kc8] = lv;
    }
}

// ---------------- Kernel 3: split-bf16 3-product MFMA GEMM + tanh·Va epilogue
__global__ __launch_bounds__(256, 1)
void gemm3_kernel(const float* __restrict__ A,        // enc [M, K] fp32
                  const u16* __restrict__ Bh_t,       // [N, K] bf16-hi
                  const u16* __restrict__ Bl_t,       // [N, K] bf16-lo
                  const float* __restrict__ dec_proj, // [B, H] (biases folded)
                  const float* __restrict__ Va_w,     // [H]
                  float* __restrict__ partials)       // [M, 16]
{
    __shared__ u16 AhS[2][BM*BK], AlS[2][BM*BK];
    __shared__ u16 BhS[2][BN*BK], BlS[2][BN*BK];

    // XCD-chunked swizzle: each XCD gets a contiguous run of 64 m-tiles x 8 nch
    const int bid = blockIdx.x;
    const int wg  = (bid & 7) * 512 + (bid >> 3);
    const int nch = wg & 7;
    const int m0  = (wg >> 3) * BM;
    const int n0  = nch * BN;

    const int tid  = threadIdx.x;
    const int lane = tid & 63;
    const int wid  = tid >> 6;
    const int wm   = wid >> 1, wn = wid & 1;

    // staging decomposition: A two tasks (r0,c0),(r1,c0); B two chunks at row rb
    const int r0 = tid >> 2, r1 = r0 + 64, c0 = tid & 3;
    const int rb = tid >> 1, cb0 = (tid & 1) * 2, cb1 = cb0 + 1;
    // swizzled LDS offsets (u16 units): off(r,c) = r*32 + ((c ^ ((r>>2)&3))<<3)
    const int a_off0 = r0*BK + ((c0 ^ ((r0>>2)&3)) << 3);
    const int a_off1 = r1*BK + ((c0 ^ ((r1>>2)&3)) << 3);
    const int b_off0 = rb*BK + ((cb0 ^ ((rb>>2)&3)) << 3);
    const int b_off1 = rb*BK + ((cb1 ^ ((rb>>2)&3)) << 3);

    f32x4 acc[4][4];
    #pragma unroll
    for (int i = 0; i < 4; ++i)
        #pragma unroll
        for (int j = 0; j < 4; ++j) acc[i][j] = (f32x4){0.f,0.f,0.f,0.f};

    float4 av0, av1, av2, av3;
    s16x8 bhv0, bhv1, blv0, blv1;

    auto load_tile = [&](int kt) {
        const float* Ab = A + (size_t)m0*HH + kt*BK;
        av0 = *(const float4*)(Ab + (size_t)r0*HH + c0*8);
        av1 = *(const float4*)(Ab + (size_t)r0*HH + c0*8 + 4);
        av2 = *(const float4*)(Ab + (size_t)r1*HH + c0*8);
        av3 = *(const float4*)(Ab + (size_t)r1*HH + c0*8 + 4);
        const u16* Bhb = Bh_t + (size_t)(n0 + rb)*HH + kt*BK;
        const u16* Blb = Bl_t + (size_t)(n0 + rb)*HH + kt*BK;
        bhv0 = *(const s16x8*)(Bhb + cb0*8);
        bhv1 = *(const s16x8*)(Bhb + cb1*8);
        blv0 = *(const s16x8*)(Blb + cb0*8);
        blv1 = *(const s16x8*)(Blb + cb1*8);
    };
    auto split8 = [&](float4 v0, float4 v1, s16x8& h, s16x8& l) {
        float x[8] = {v0.x,v0.y,v0.z,v0.w,v1.x,v1.y,v1.z,v1.w};
        #pragma unroll
        for (int j = 0; j < 8; ++j) {
            u16 hh, ll; split1(x[j], hh, ll);
            h[j] = (short)hh; l[j] = (short)ll;
        }
    };
    auto write_tile = [&](int wb) {
        s16x8 h, l;
        split8(av0, av1, h, l);
        *(s16x8*)&AhS[wb][a_off0] = h; *(s16x8*)&AlS[wb][a_off0] = l;
        split8(av2, av3, h, l);
        *(s16x8*)&AhS[wb][a_off1] = h; *(s16x8*)&AlS[wb][a_off1] = l;
        *(s16x8*)&BhS[wb][b_off0] = bhv0; *(s16x8*)&BhS[wb][b_off1] = bhv1;
        *(s16x8*)&BlS[wb][b_off0] = blv0; *(s16x8*)&BlS[wb][b_off1] = blv1;
    };

    const int lr = lane & 15, lk = lane >> 4;
    const int sx = (lr >> 2) & 3;          // XOR term is f/wave-independent
    const int ox = (lk ^ sx) << 3;

    auto compute = [&](int cb) {
        s16x8 ah[4], al[4], bh[4], bl[4];
        #pragma unroll
        for (int f = 0; f < 4; ++f) {
            const int ra  = wm*64 + f*16 + lr;
            const int oa  = ra*BK + ox;
            ah[f] = *(const s16x8*)&AhS[cb][oa];
            al[f] = *(const s16x8*)&AlS[cb][oa];
            const int rb2 = wn*64 + f*16 + lr;
            const int ob  = rb2*BK + ox;
            bh[f] = *(const s16x8*)&BhS[cb][ob];
            bl[f] = *(const s16x8*)&BlS[cb][ob];
        }
        #pragma unroll
        for (int i = 0; i < 4; ++i)
            #pragma unroll
            for (int j = 0; j < 4; ++j) {
                acc[i][j] = __builtin_amdgcn_mfma_f32_16x16x32_bf16(ah[i], bh[j], acc[i][j], 0, 0, 0);
                acc[i][j] = __builtin_amdgcn_mfma_f32_16x16x32_bf16(ah[i], bl[j], acc[i][j], 0, 0, 0);
                acc[i][j] = __builtin_amdgcn_mfma_f32_16x16x32_bf16(al[i], bh[j], acc[i][j], 0, 0, 0);
            }
    };

    load_tile(0);
    write_tile(0);
    __syncthreads();
    int buf = 0;
    for (int kt = 0; kt < NT; ++kt) {
        const bool hn = (kt + 1 < NT);
        if (hn) load_tile(kt + 1);   // issue global loads early; hide under MFMA
        compute(buf);
        if (hn) write_tile(buf ^ 1);
        __syncthreads();
        buf ^= 1;
    }

    // epilogue: rowsum over this block's 128 n-cols of Va[n]*tanh(C+dp[n])
    const int bidx = m0 >> 11;            // batch index (2048 rows per batch)
    float dp[4], va[4];
    #pragma unroll
    for (int f = 0; f < 4; ++f) {
        const int n = n0 + wn*64 + f*16 + lr;
        dp[f] = dec_proj[bidx*HH + n];
        va[f] = Va_w[n];
    }
    #pragma unroll
    for (int i = 0; i < 4; ++i) {
        #pragma unroll
        for (int r = 0; r < 4; ++r) {
            float s = 0.f;
            #pragma unroll
            for (int f = 0; f < 4; ++f)
                s += va[f] * tanhf(acc[i][f][r] + dp[f]);
            s += __shfl_xor(s, 1, 64);
            s += __shfl_xor(s, 2, 64);
            s += __shfl_xor(s, 4, 64);
            s += __shfl_xor(s, 8, 64);
            if (lr == 0) {
                const int m = m0 + wm*64 + i*16 + lk*4 + r;
                partials[(size_t)m*16 + nch*2 + wn] = s;
            }
        }
    }
}

// ---------------- Kernel 4: sum 16 partials + Va_b, mask, softmax over S
__global__ void softmax_kernel(const float* __restrict__ partials,
                               const int* __restrict__ mask,
                               const float* __restrict__ vb_ptr,
                               float* __restrict__ out)
{
    const int b   = blockIdx.x;
    const int tid = threadIdx.x;   // 256, each handles 8 s-positions
    __shared__ float sred[8];
    const float vb = vb_ptr[0];
    float sc[8];
    float mymax = -INFINITY;
    #pragma unroll
    for (int i = 0; i < 8; ++i) {
        const int s = i*256 + tid;
        const float4* p = (const float4*)&partials[((size_t)b*SS + s)*16];
        const float4 x = p[0], y = p[1], z = p[2], w = p[3];
        float v = (((x.x+x.y)+(x.z+x.w)) + ((y.x+y.y)+(y.z+y.w)))
                + (((z.x+z.y)+(z.z+z.w)) + ((w.x+w.y)+(w.z+w.w))) + vb;
        if (mask[b*SS + s] == 0) v = -1e9f;
        sc[i] = v;
        mymax = fmaxf(mymax, v);
    }
    #pragma unroll
    for (int off = 1; off < 64; off <<= 1)
        mymax = fmaxf(mymax, __shfl_xor(mymax, off, 64));
    const int wave = tid >> 6, lane = tid & 63;
    if (lane == 0) sred[wave] = mymax;
    __syncthreads();
    const float bmax = fmaxf(fmaxf(sred[0], sred[1]), fmaxf(sred[2], sred[3]));
    float ex[8], mysum = 0.f;
    #pragma unroll
    for (int i = 0; i < 8; ++i) {
        ex[i] = __expf(sc[i] - bmax);
        mysum += ex[i];
    }
    #pragma unroll
    for (int off = 1; off < 64; off <<= 1)
        mysum += __shfl_xor(mysum, off, 64);
    if (lane == 0) sred[4 + wave] = mysum;
    __syncthreads();
    const float inv = 1.f / (sred[4] + sred[5] + sred[6] + sred[7]);
    #pragma unroll
    for (int i = 0; i < 8; ++i)
        out[(size_t)b*SS + i*256 + tid] = ex[i] * inv;
}

extern "C" void kernel_launch(void* const* d_in, const int* in_sizes, int n_in,
                              void* d_out, int out_size, void* d_ws, size_t ws_size,
                              hipStream_t stream) {
    const float* dh   = (const float*)d_in[0];
    const float* enc  = (const float*)d_in[1];
    const int*   mask = (const int*)d_in[2];
    const float* Wa_w = (const float*)d_in[3];
    const float* Wa_b = (const float*)d_in[4];
    const float* Ua_w = (const float*)d_in[5];
    const float* Ua_b = (const float*)d_in[6];
    const float* Va_w = (const float*)d_in[7];
    const float* Va_b = (const float*)d_in[8];
    float* out = (float*)d_out;

    float* dec_proj = (float*)d_ws;                       // [B,H]    128 KB
    float* partials = dec_proj + BB*HH;                   // [M,16]   4 MB
    u16*   Bh_t     = (u16*)(partials + (size_t)MT*16);   // [N,K]    2 MB
    u16*   Bl_t     = Bh_t + (size_t)HH*HH;               // [N,K]    2 MB

    dec_proj_kernel<<<dim3(BB, 4), 256, 0, stream>>>(dh, Wa_w, Wa_b, Ua_b, dec_proj);
    transpose_convert_kernel<<<dim3(HH/64, HH/64), 256, 0, stream>>>(Ua_w, Bh_t, Bl_t);
    gemm3_kernel<<<(MT/BM)*NCH, 256, 0, stream>>>(enc, Bh_t, Bl_t, dec_proj, Va_w, partials);
    softmax_kernel<<<BB, 256, 0, stream>>>(partials, mask, Va_b, out);
}